// Round 2
// baseline (10211.924 us; speedup 1.0000x reference)
//
#include <hip/hip_runtime.h>
#include <stdint.h>

#define NPER 8192
#define NB 4
#define MPER 4096
#define MTOT (NB*MPER)      // 16384
#define KNB 64
#define CIN 64
#define R2C 0.04f           // f32-nearest of python 0.2*0.2 (NOT 0.2f*0.2f!)

// d_out (floats): x_out [MTOT*128] | pos_out [MTOT*3] | batch_out [MTOT]
#define POSOUT_OFF (MTOT*128)
#define BATCH_OFF  (MTOT*128 + MTOT*3)

// ws: nbr u16 [MTOT*64] @0 (2MB) | cnt i32 [MTOT] @2MB (64KB)

typedef float v2f __attribute__((ext_vector_type(2)));

// ---------------------------------------------------------------- K1: FPS
// One block per cloud. 256 thr, 32 pts/thread (16 float2 pairs) in registers.
// Exactness: d2 = ((dx*dx + dy*dy) + dz*dz) with contract(off) -> scalar or
// v_pk_{mul,add}_f32, both IEEE rn = bitwise numpy. Reduction = atomicMax of
// d2 BITS (nonneg floats: bit order == value order, max is exact) into 16
// spread LDS slots -> no shfl chains. Tie-break = np.argmax first-max via
// exact-equality claim + atomicMin (idx<<32|coord_bits). Centroids buffered
// in LDS, flushed coalesced at the end (no per-iter global store).
#define FPS_T 256
#define NPAIR 16            // 32 pts/thread as 16 float2
#define NSLOT 16

__global__ __launch_bounds__(256) void k_fps(const float* __restrict__ pos,
                                             float* __restrict__ dout)
{
#pragma clang fp contract(off)
  const int b = blockIdx.x;
  const int tid = threadIdx.x;
  const float* pb = pos + (size_t)b * NPER * 3;
  float* qo = dout + POSOUT_OFF + (size_t)b * MPER * 3;

  __shared__ __align__(64) unsigned gmax[3][NSLOT];  // d2-bits atomicMax slots
  __shared__ unsigned long long pk[2][3];            // claim slots
  __shared__ __align__(16) float qbuf[MPER*3];       // 48 KB centroid buffer

  v2f X[NPAIR], Y[NPAIR], Z[NPAIR], D[NPAIR];
#pragma unroll
  for (int k = 0; k < NPAIR; ++k) {
    int i0 = tid + (2*k) * FPS_T, i1 = i0 + FPS_T;
    X[k].x = pb[i0*3+0]; X[k].y = pb[i1*3+0];
    Y[k].x = pb[i0*3+1]; Y[k].y = pb[i1*3+1];
    Z[k].x = pb[i0*3+2]; Z[k].y = pb[i1*3+2];
    D[k].x = 3.402823466e+38f; D[k].y = 3.402823466e+38f;
  }
  if (tid == 0) {
    // seed selection = point 0 (tid0's pair0 .x IS point 0)
    pk[0][0] = ((unsigned long long)0u << 32) | __float_as_uint(X[0].x);
    pk[0][1] = ((unsigned long long)0u << 32) | __float_as_uint(Y[0].x);
    pk[0][2] = ((unsigned long long)0u << 32) | __float_as_uint(Z[0].x);
    pk[1][0] = ~0ull; pk[1][1] = ~0ull; pk[1][2] = ~0ull;
  }
  if (tid < NSLOT) { gmax[0][tid] = 0u; gmax[1][tid] = 0u; gmax[2][tid] = 0u; }
  __syncthreads();

  for (int m = 1; m < MPER; ++m) {
    const int sA = m % 3;               // gmax set this iter
    const int pr = (m-1) & 1, pw = m & 1;
    // ---- A phase: read selection, update D, publish local max ----
    unsigned long long p0 = pk[pr][0], p1 = pk[pr][1], p2 = pk[pr][2];
    float nx = __uint_as_float((unsigned)p0);
    float ny = __uint_as_float((unsigned)p1);
    float nz = __uint_as_float((unsigned)p2);
    if (tid == 0) {                     // record row m-1 into LDS buffer
      qbuf[(m-1)*3+0] = nx; qbuf[(m-1)*3+1] = ny; qbuf[(m-1)*3+2] = nz;
    }
    if (tid < NSLOT) gmax[(m+1) % 3][tid] = 0u;   // reset next iter's set
    v2f nx2 = {nx, nx}, ny2 = {ny, ny}, nz2 = {nz, nz};
    float lv = 0.0f;
#pragma unroll
    for (int k = 0; k < NPAIR; ++k) {
      v2f dx = X[k] - nx2;
      v2f dy = Y[k] - ny2;
      v2f dz = Z[k] - nz2;
      v2f s = (dx*dx + dy*dy) + dz*dz;  // ((x+y)+z), rn, no fma
      D[k].x = fminf(D[k].x, s.x);
      D[k].y = fminf(D[k].y, s.y);
      lv = fmaxf(lv, fmaxf(D[k].x, D[k].y));
    }
    atomicMax(&gmax[sA][tid & (NSLOT-1)], __float_as_uint(lv));
    __syncthreads();                    // B1
    // ---- B phase: global max, exact claim ----
    unsigned gm0 = gmax[sA][0],  gm1 = gmax[sA][1];
    unsigned gm2 = gmax[sA][2],  gm3 = gmax[sA][3];
    unsigned gm4 = gmax[sA][4],  gm5 = gmax[sA][5];
    unsigned gm6 = gmax[sA][6],  gm7 = gmax[sA][7];
    unsigned gm8 = gmax[sA][8],  gm9 = gmax[sA][9];
    unsigned gmA = gmax[sA][10], gmB = gmax[sA][11];
    unsigned gmC = gmax[sA][12], gmD = gmax[sA][13];
    unsigned gmE = gmax[sA][14], gmF = gmax[sA][15];
    gm0 = max(gm0, gm1); gm2 = max(gm2, gm3);
    gm4 = max(gm4, gm5); gm6 = max(gm6, gm7);
    gm8 = max(gm8, gm9); gmA = max(gmA, gmB);
    gmC = max(gmC, gmD); gmE = max(gmE, gmF);
    gm0 = max(gm0, gm2); gm4 = max(gm4, gm6);
    gm8 = max(gm8, gmA); gmC = max(gmC, gmE);
    gm0 = max(gm0, gm4); gm8 = max(gm8, gmC);
    const unsigned gmb = max(gm0, gm8);
    // reset the pk set read this iter (reused for claims at iter m+1)
    if (tid >= 32 && tid < 35) pk[pr][tid-32] = ~0ull;
    if (__float_as_uint(lv) == gmb) {
#pragma unroll
      for (int k = 0; k < NPAIR; ++k) {
        if (__float_as_uint(D[k].x) == gmb) {
          unsigned long long hi =
            ((unsigned long long)(unsigned)(tid + (2*k)*FPS_T)) << 32;
          atomicMin(&pk[pw][0], hi | __float_as_uint(X[k].x));
          atomicMin(&pk[pw][1], hi | __float_as_uint(Y[k].x));
          atomicMin(&pk[pw][2], hi | __float_as_uint(Z[k].x));
          break;
        }
        if (__float_as_uint(D[k].y) == gmb) {
          unsigned long long hi =
            ((unsigned long long)(unsigned)(tid + (2*k+1)*FPS_T)) << 32;
          atomicMin(&pk[pw][0], hi | __float_as_uint(X[k].y));
          atomicMin(&pk[pw][1], hi | __float_as_uint(Y[k].y));
          atomicMin(&pk[pw][2], hi | __float_as_uint(Z[k].y));
          break;
        }
      }
    }
    __syncthreads();                    // B2
  }
  if (tid == 0) {                       // last selection (m = MPER-1)
    unsigned long long p0 = pk[(MPER-1)&1][0];
    unsigned long long p1 = pk[(MPER-1)&1][1];
    unsigned long long p2 = pk[(MPER-1)&1][2];
    qbuf[(MPER-1)*3+0] = __uint_as_float((unsigned)p0);
    qbuf[(MPER-1)*3+1] = __uint_as_float((unsigned)p1);
    qbuf[(MPER-1)*3+2] = __uint_as_float((unsigned)p2);
  }
  __syncthreads();
  // coalesced flush: 12288 floats = 3072 float4
  for (int e = tid; e < MPER*3/4; e += FPS_T)
    ((float4*)qo)[e] = ((const float4*)qbuf)[e];
}

// ------------------------------------------------- K2: radius + top-K select
// One wave per centroid. Candidates (d2<=R2) appended via ballot-prefix into
// LDS as u64 key = (d2_bits<<32)|idx (d2>=0 so float bits are order-monotone;
// idx in low bits reproduces top_k's lower-index tie-break). Bitonic sort 512.
#define SCAP 512
__global__ __launch_bounds__(256) void k_radius(const float* __restrict__ pos,
    float* __restrict__ dout, unsigned short* __restrict__ nbr,
    int* __restrict__ cnt)
{
  __shared__ unsigned long long cand[4][SCAP];
  const int wid = threadIdx.x >> 6, lane = threadIdx.x & 63;
  const int m = blockIdx.x * 4 + wid;
  const int b = m >> 12;
  const float* pb = pos + (size_t)b * NPER * 3;
  const float* q = dout + POSOUT_OFF + (size_t)m * 3;
  const float qx = q[0], qy = q[1], qz = q[2];
  unsigned cw = 0;
  for (int it = 0; it < NPER/64; ++it) {
    int i = (it << 6) + lane;
    float dx = __fsub_rn(qx, pb[i*3+0]);
    float dy = __fsub_rn(qy, pb[i*3+1]);
    float dz = __fsub_rn(qz, pb[i*3+2]);
    float d2 = __fadd_rn(__fadd_rn(__fmul_rn(dx,dx), __fmul_rn(dy,dy)),
                         __fmul_rn(dz,dz));
    bool in = (d2 <= R2C);
    unsigned long long mk = __ballot(in);
    unsigned pre = (unsigned)__popcll(mk & ((1ull << lane) - 1ull));
    if (in) {
      unsigned slot = cw + pre;
      if (slot < SCAP)
        cand[wid][slot] =
          (((unsigned long long)__float_as_uint(d2)) << 32) | (unsigned)i;
    }
    cw += (unsigned)__popcll(mk);
  }
  if (cw > SCAP) cw = SCAP;   // statistically unreachable (lambda_max ~274)
  for (int s = (int)cw + lane; s < SCAP; s += 64) cand[wid][s] = ~0ull;
  __syncthreads();
  for (int k = 2; k <= SCAP; k <<= 1) {
    for (int j = k >> 1; j > 0; j >>= 1) {
#pragma unroll
      for (int s = 0; s < SCAP/128; ++s) {
        int t = lane + (s << 6);
        int e = ((t & ~(j-1)) << 1) | (t & (j-1));
        int p = e | j;
        unsigned long long a = cand[wid][e], c = cand[wid][p];
        bool asc = ((e & k) == 0);
        bool sw = asc ? (a > c) : (a < c);
        if (sw) { cand[wid][e] = c; cand[wid][p] = a; }
      }
      __syncthreads();
    }
  }
  int kk = (int)cw; if (kk > KNB) kk = KNB;
  unsigned long long key = cand[wid][lane];
  nbr[(size_t)m*KNB + lane] =
    (lane < kk) ? (unsigned short)(key & 0xFFFFull) : (unsigned short)0;
  if (lane == 0) {
    cnt[m] = kk;
    dout[BATCH_OFF + m] = (float)b;   // batch_out (buffer read as f32)
  }
}

// --------------------------------------------- K3: gather -> MLP -> max (fp32)
// One 128-thr block per centroid. featT[ch][j] (stride 68) + W1 in LDS;
// stage B: 8j x 4h register tile; h1T reuses featT buffer; W2 streamed in
// 16-row chunks through the W1 buffer; stage C: 8j x 8c tile; masked
// shuffle-max over j, write 128 outputs.
__global__ __launch_bounds__(128) void k_conv(
    const float* __restrict__ x, const float* __restrict__ pos,
    const float* __restrict__ W1, const float* __restrict__ b1,
    const float* __restrict__ W2, const float* __restrict__ b2,
    const unsigned short* __restrict__ nbr, const int* __restrict__ cntp,
    float* __restrict__ dout)
{
  __shared__ __align__(16) float bufA[68*68];   // featT then h1T (stride 68)
  __shared__ __align__(16) float bufB[68*68];   // W1 then W2 chunks (str 136)
  __shared__ unsigned short nbr_s[64];
  __shared__ float qv[3];
  __shared__ int cnt_s;
  const int t = threadIdx.x;
  const int m = blockIdx.x;
  const int b = m >> 12;
  if (t < 64) nbr_s[t] = nbr[(size_t)m*KNB + t];
  else if (t == 64) cnt_s = cntp[m];
  else if (t >= 65 && t < 68) qv[t-65] = dout[POSOUT_OFF + (size_t)m*3 + (t-65)];
  for (int e = t; e < 67*64; e += 128) {
    int ch = e >> 6, h = e & 63;
    bufB[ch*68 + h] = W1[e];
  }
  __syncthreads();
  {                                   // gather x rows -> featT rows 0..63
    const int ch = t & 63, jj = t >> 6;
    const size_t xb = (size_t)b * NPER * CIN;
    for (int j0 = 0; j0 < 64; j0 += 2) {
      int j = j0 + jj;
      int r = nbr_s[j];
      bufA[ch*68 + j] = x[xb + (size_t)r*CIN + ch];
    }
  }
  {                                   // rel -> rows 64..66
    const size_t pbb = (size_t)b * NPER * 3;
    for (int e = t; e < 192; e += 128) {
      int j = e & 63, d = e >> 6;
      int r = nbr_s[j];
      bufA[(64+d)*68 + j] = pos[pbb + (size_t)r*3 + d] - qv[d];
    }
  }
  __syncthreads();

  const int jg = t & 7, hg = t >> 3;
  const int j0 = jg << 3;
  const int h0 = hg << 2;
  float acc[4][8];
#pragma unroll
  for (int hh = 0; hh < 4; ++hh)
#pragma unroll
    for (int j = 0; j < 8; ++j) acc[hh][j] = 0.0f;
  for (int ch = 0; ch < 67; ++ch) {
    const float4 fa = *(const float4*)&bufA[ch*68 + j0];
    const float4 fb = *(const float4*)&bufA[ch*68 + j0 + 4];
    const float4 w  = *(const float4*)&bufB[ch*68 + h0];
    const float ws4[4] = {w.x, w.y, w.z, w.w};
    const float fj[8] = {fa.x, fa.y, fa.z, fa.w, fb.x, fb.y, fb.z, fb.w};
#pragma unroll
    for (int hh = 0; hh < 4; ++hh)
#pragma unroll
      for (int j = 0; j < 8; ++j)
        acc[hh][j] += ws4[hh] * fj[j];
  }
  __syncthreads();                    // featT + W1 reads complete
  {                                   // h1T = relu(acc + b1) into bufA
    const float4 bb = *(const float4*)&b1[h0];
    const float bv[4] = {bb.x, bb.y, bb.z, bb.w};
#pragma unroll
    for (int hh = 0; hh < 4; ++hh) {
      float4 o0, o1;
      o0.x = fmaxf(acc[hh][0] + bv[hh], 0.0f);
      o0.y = fmaxf(acc[hh][1] + bv[hh], 0.0f);
      o0.z = fmaxf(acc[hh][2] + bv[hh], 0.0f);
      o0.w = fmaxf(acc[hh][3] + bv[hh], 0.0f);
      o1.x = fmaxf(acc[hh][4] + bv[hh], 0.0f);
      o1.y = fmaxf(acc[hh][5] + bv[hh], 0.0f);
      o1.z = fmaxf(acc[hh][6] + bv[hh], 0.0f);
      o1.w = fmaxf(acc[hh][7] + bv[hh], 0.0f);
      *(float4*)&bufA[(h0+hh)*68 + j0] = o0;
      *(float4*)&bufA[(h0+hh)*68 + j0 + 4] = o1;
    }
  }
  const int c0 = hg << 3;             // stage C: 8j x 8c
  float acc2[8][8];                   // [c][j]
#pragma unroll
  for (int c = 0; c < 8; ++c)
#pragma unroll
    for (int j = 0; j < 8; ++j) acc2[c][j] = 0.0f;
  for (int hc = 0; hc < 64; hc += 16) {
    __syncthreads();                  // h1T ready / prior chunk consumed
    for (int e = t; e < 16*128; e += 128) {
      int hh = e >> 7, c = e & 127;
      bufB[hh*136 + c] = W2[(size_t)(hc+hh)*128 + c];
    }
    __syncthreads();
#pragma unroll
    for (int h = 0; h < 16; ++h) {
      const float4 ja = *(const float4*)&bufA[(hc+h)*68 + j0];
      const float4 jb = *(const float4*)&bufA[(hc+h)*68 + j0 + 4];
      const float4 wa = *(const float4*)&bufB[h*136 + c0];
      const float4 wb = *(const float4*)&bufB[h*136 + c0 + 4];
      const float hv[8] = {ja.x, ja.y, ja.z, ja.w, jb.x, jb.y, jb.z, jb.w};
      const float wv[8] = {wa.x, wa.y, wa.z, wa.w, wb.x, wb.y, wb.z, wb.w};
#pragma unroll
      for (int c = 0; c < 8; ++c)
#pragma unroll
        for (int j = 0; j < 8; ++j)
          acc2[c][j] += wv[c] * hv[j];
    }
  }
  const int cntv = cnt_s;
  const float4 b2a = *(const float4*)&b2[c0];
  const float4 b2b = *(const float4*)&b2[c0 + 4];
  const float bv2[8] = {b2a.x, b2a.y, b2a.z, b2a.w, b2b.x, b2b.y, b2b.z, b2b.w};
  float best[8];
#pragma unroll
  for (int c = 0; c < 8; ++c) {
    float v = -3.402823466e+38f;
#pragma unroll
    for (int j = 0; j < 8; ++j) {
      float hv = fmaxf(acc2[c][j] + bv2[c], 0.0f);
      v = (j0 + j < cntv) ? fmaxf(v, hv) : v;
    }
    best[c] = v;
  }
#pragma unroll
  for (int off = 1; off < 8; off <<= 1)
#pragma unroll
    for (int c = 0; c < 8; ++c)
      best[c] = fmaxf(best[c], __shfl_xor(best[c], off));
  if (jg == 0) {
    float4 o0 = {best[0], best[1], best[2], best[3]};
    float4 o1 = {best[4], best[5], best[6], best[7]};
    *(float4*)&dout[(size_t)m*128 + c0] = o0;
    *(float4*)&dout[(size_t)m*128 + c0 + 4] = o1;
  }
}

extern "C" void kernel_launch(void* const* d_in, const int* in_sizes, int n_in,
                              void* d_out, int out_size, void* d_ws, size_t ws_size,
                              hipStream_t stream) {
  const float* x   = (const float*)d_in[0];
  const float* pos = (const float*)d_in[1];
  // d_in[2] = batch (layout known statically, unused)
  const float* W1  = (const float*)d_in[3];
  const float* b1  = (const float*)d_in[4];
  const float* W2  = (const float*)d_in[5];
  const float* b2  = (const float*)d_in[6];
  float* dout = (float*)d_out;
  unsigned short* nbr = (unsigned short*)d_ws;
  int* cnt = (int*)((char*)d_ws + (size_t)MTOT*KNB*2);

  hipLaunchKernelGGL(k_fps,    dim3(NB),     dim3(FPS_T), 0, stream, pos, dout);
  hipLaunchKernelGGL(k_radius, dim3(MTOT/4), dim3(256),   0, stream, pos, dout, nbr, cnt);
  hipLaunchKernelGGL(k_conv,   dim3(MTOT),   dim3(128),   0, stream,
                     x, pos, W1, b1, W2, b2, nbr, cnt, dout);
}

// Round 3
// 5673.434 us; speedup vs baseline: 1.8000x; 1.8000x over previous
//
#include <hip/hip_runtime.h>
#include <stdint.h>

#define NPER 8192
#define NB 4
#define MPER 4096
#define MTOT (NB*MPER)      // 16384
#define KNB 64
#define CIN 64
#define R2C 0.04f           // f32-nearest of python 0.2*0.2 (NOT 0.2f*0.2f!)

// d_out (floats): x_out [MTOT*128] | pos_out [MTOT*3] | batch_out [MTOT]
#define POSOUT_OFF (MTOT*128)
#define BATCH_OFF  (MTOT*128 + MTOT*3)

// ws: nbr u16 [MTOT*64] @0 (2MB) | cnt i32 [MTOT] @2MB (64KB)

// ---------------------------------------------------------------- K1: FPS
// One block per cloud. 1024 thr (16 waves, 4/SIMD), 8 pts/thread in regs.
// ONE barrier per iteration:
//   update D (exact rn arithmetic, ((dx2+dy2)+dz2), no fma)
//   -> in-thread strict-> argmax (first-max kept)
//   -> pack u64 (d2_bits<<32)|(8191-idx)  [max == np.argmax w/ first-max tie]
//   -> 6-level wave shfl_xor u64 max -> lane0 LDS atomicMax into 3-phase slot
//   -> __syncthreads -> all read slot -> winner idx
// Winner coords come from a same-address global load (L2-resident, ~250cyc)
// -- no claim phase, no coord publish, no second barrier. Centroids buffered
// in LDS qbuf (48 KB), flushed coalesced at the end.
#define FPS_T 1024
#define PTS 8

__global__ __launch_bounds__(1024) void k_fps(const float* __restrict__ pos,
                                              float* __restrict__ dout)
{
  const int b = blockIdx.x;
  const int tid = threadIdx.x;
  const float* pb = pos + (size_t)b * NPER * 3;
  float* qo = dout + POSOUT_OFF + (size_t)b * MPER * 3;

  __shared__ unsigned long long slotU[3];       // 3-phase winner slots
  __shared__ __align__(16) float qbuf[MPER*3];  // 48 KB centroid buffer

  float X[PTS], Y[PTS], Z[PTS], D[PTS];
#pragma unroll
  for (int k = 0; k < PTS; ++k) {
    int i = k * FPS_T + tid;
    X[k] = pb[i*3+0]; Y[k] = pb[i*3+1]; Z[k] = pb[i*3+2];
    D[k] = 3.402823466e+38f;
  }
  if (tid == 0) { slotU[0] = 0ull; slotU[1] = 0ull; slotU[2] = 0ull; }
  __syncthreads();

  int idx_prev = 0;                 // seed selection = point 0
  for (int m = 1; m < MPER; ++m) {
    // winner (m-1) coords: all-lanes-same-address global load (L2 hot)
    const float cx = pb[idx_prev*3+0];
    const float cy = pb[idx_prev*3+1];
    const float cz = pb[idx_prev*3+2];
    if (tid == 0) {                 // record row m-1 into LDS buffer
      qbuf[(m-1)*3+0] = cx; qbuf[(m-1)*3+1] = cy; qbuf[(m-1)*3+2] = cz;
    }
    if (tid == 1) slotU[(m+1) % 3] = 0ull;   // reset future slot (phase-safe)

    float best = -1.0f; int bi = 0;
#pragma unroll
    for (int k = 0; k < PTS; ++k) {
      float dx = __fsub_rn(X[k], cx);
      float dy = __fsub_rn(Y[k], cy);
      float dz = __fsub_rn(Z[k], cz);
      float s = __fadd_rn(__fadd_rn(__fmul_rn(dx,dx), __fmul_rn(dy,dy)),
                          __fmul_rn(dz,dz));
      float dnew = fminf(D[k], s);
      D[k] = dnew;
      bool g = dnew > best;         // strict > keeps smallest k on ties
      best = g ? dnew : best;
      bi   = g ? k    : bi;
    }
    // pack: max(d2) then min(global idx) on ties -> exact np.argmax
    unsigned long long pk =
      ((unsigned long long)__float_as_uint(best) << 32) |
      (unsigned)(NPER - 1 - (bi * FPS_T + tid));
#pragma unroll
    for (int off = 1; off < 64; off <<= 1) {
      unsigned long long o = __shfl_xor(pk, off);
      pk = (o > pk) ? o : pk;
    }
    if ((tid & 63) == 0) atomicMax(&slotU[m % 3], pk);
    __syncthreads();
    idx_prev = NPER - 1 - (int)(unsigned)slotU[m % 3];
  }
  {                                  // final selection (m = MPER-1)
    const float cx = pb[idx_prev*3+0];
    const float cy = pb[idx_prev*3+1];
    const float cz = pb[idx_prev*3+2];
    if (tid == 0) {
      qbuf[(MPER-1)*3+0] = cx; qbuf[(MPER-1)*3+1] = cy; qbuf[(MPER-1)*3+2] = cz;
    }
  }
  __syncthreads();
  // coalesced flush: 12288 floats = 3072 float4
  for (int e = tid; e < MPER*3/4; e += FPS_T)
    ((float4*)qo)[e] = ((const float4*)qbuf)[e];
}

// ------------------------------------------------- K2: radius + top-K select
// One wave per centroid. Candidates (d2<=R2) appended via ballot-prefix into
// LDS as u64 key = (d2_bits<<32)|idx (d2>=0 so float bits are order-monotone;
// idx in low bits reproduces top_k's lower-index tie-break). Bitonic sort 512.
#define SCAP 512
__global__ __launch_bounds__(256) void k_radius(const float* __restrict__ pos,
    float* __restrict__ dout, unsigned short* __restrict__ nbr,
    int* __restrict__ cnt)
{
  __shared__ unsigned long long cand[4][SCAP];
  const int wid = threadIdx.x >> 6, lane = threadIdx.x & 63;
  const int m = blockIdx.x * 4 + wid;
  const int b = m >> 12;
  const float* pb = pos + (size_t)b * NPER * 3;
  const float* q = dout + POSOUT_OFF + (size_t)m * 3;
  const float qx = q[0], qy = q[1], qz = q[2];
  unsigned cw = 0;
  for (int it = 0; it < NPER/64; ++it) {
    int i = (it << 6) + lane;
    float dx = __fsub_rn(qx, pb[i*3+0]);
    float dy = __fsub_rn(qy, pb[i*3+1]);
    float dz = __fsub_rn(qz, pb[i*3+2]);
    float d2 = __fadd_rn(__fadd_rn(__fmul_rn(dx,dx), __fmul_rn(dy,dy)),
                         __fmul_rn(dz,dz));
    bool in = (d2 <= R2C);
    unsigned long long mk = __ballot(in);
    unsigned pre = (unsigned)__popcll(mk & ((1ull << lane) - 1ull));
    if (in) {
      unsigned slot = cw + pre;
      if (slot < SCAP)
        cand[wid][slot] =
          (((unsigned long long)__float_as_uint(d2)) << 32) | (unsigned)i;
    }
    cw += (unsigned)__popcll(mk);
  }
  if (cw > SCAP) cw = SCAP;   // statistically unreachable (lambda_max ~274)
  for (int s = (int)cw + lane; s < SCAP; s += 64) cand[wid][s] = ~0ull;
  __syncthreads();
  for (int k = 2; k <= SCAP; k <<= 1) {
    for (int j = k >> 1; j > 0; j >>= 1) {
#pragma unroll
      for (int s = 0; s < SCAP/128; ++s) {
        int t = lane + (s << 6);
        int e = ((t & ~(j-1)) << 1) | (t & (j-1));
        int p = e | j;
        unsigned long long a = cand[wid][e], c = cand[wid][p];
        bool asc = ((e & k) == 0);
        bool sw = asc ? (a > c) : (a < c);
        if (sw) { cand[wid][e] = c; cand[wid][p] = a; }
      }
      __syncthreads();
    }
  }
  int kk = (int)cw; if (kk > KNB) kk = KNB;
  unsigned long long key = cand[wid][lane];
  nbr[(size_t)m*KNB + lane] =
    (lane < kk) ? (unsigned short)(key & 0xFFFFull) : (unsigned short)0;
  if (lane == 0) {
    cnt[m] = kk;
    dout[BATCH_OFF + m] = (float)b;   // batch_out (buffer read as f32)
  }
}

// --------------------------------------------- K3: gather -> MLP -> max (fp32)
// One 128-thr block per centroid. featT[ch][j] (stride 68) + W1 in LDS;
// stage B: 8j x 4h register tile; h1T reuses featT buffer; W2 streamed in
// 16-row chunks through the W1 buffer; stage C: 8j x 8c tile; masked
// shuffle-max over j, write 128 outputs.
__global__ __launch_bounds__(128) void k_conv(
    const float* __restrict__ x, const float* __restrict__ pos,
    const float* __restrict__ W1, const float* __restrict__ b1,
    const float* __restrict__ W2, const float* __restrict__ b2,
    const unsigned short* __restrict__ nbr, const int* __restrict__ cntp,
    float* __restrict__ dout)
{
  __shared__ __align__(16) float bufA[68*68];   // featT then h1T (stride 68)
  __shared__ __align__(16) float bufB[68*68];   // W1 then W2 chunks (str 136)
  __shared__ unsigned short nbr_s[64];
  __shared__ float qv[3];
  __shared__ int cnt_s;
  const int t = threadIdx.x;
  const int m = blockIdx.x;
  const int b = m >> 12;
  if (t < 64) nbr_s[t] = nbr[(size_t)m*KNB + t];
  else if (t == 64) cnt_s = cntp[m];
  else if (t >= 65 && t < 68) qv[t-65] = dout[POSOUT_OFF + (size_t)m*3 + (t-65)];
  for (int e = t; e < 67*64; e += 128) {
    int ch = e >> 6, h = e & 63;
    bufB[ch*68 + h] = W1[e];
  }
  __syncthreads();
  {                                   // gather x rows -> featT rows 0..63
    const int ch = t & 63, jj = t >> 6;
    const size_t xb = (size_t)b * NPER * CIN;
    for (int j0 = 0; j0 < 64; j0 += 2) {
      int j = j0 + jj;
      int r = nbr_s[j];
      bufA[ch*68 + j] = x[xb + (size_t)r*CIN + ch];
    }
  }
  {                                   // rel -> rows 64..66
    const size_t pbb = (size_t)b * NPER * 3;
    for (int e = t; e < 192; e += 128) {
      int j = e & 63, d = e >> 6;
      int r = nbr_s[j];
      bufA[(64+d)*68 + j] = pos[pbb + (size_t)r*3 + d] - qv[d];
    }
  }
  __syncthreads();

  const int jg = t & 7, hg = t >> 3;
  const int j0 = jg << 3;
  const int h0 = hg << 2;
  float acc[4][8];
#pragma unroll
  for (int hh = 0; hh < 4; ++hh)
#pragma unroll
    for (int j = 0; j < 8; ++j) acc[hh][j] = 0.0f;
  for (int ch = 0; ch < 67; ++ch) {
    const float4 fa = *(const float4*)&bufA[ch*68 + j0];
    const float4 fb = *(const float4*)&bufA[ch*68 + j0 + 4];
    const float4 w  = *(const float4*)&bufB[ch*68 + h0];
    const float ws4[4] = {w.x, w.y, w.z, w.w};
    const float fj[8] = {fa.x, fa.y, fa.z, fa.w, fb.x, fb.y, fb.z, fb.w};
#pragma unroll
    for (int hh = 0; hh < 4; ++hh)
#pragma unroll
      for (int j = 0; j < 8; ++j)
        acc[hh][j] += ws4[hh] * fj[j];
  }
  __syncthreads();                    // featT + W1 reads complete
  {                                   // h1T = relu(acc + b1) into bufA
    const float4 bb = *(const float4*)&b1[h0];
    const float bv[4] = {bb.x, bb.y, bb.z, bb.w};
#pragma unroll
    for (int hh = 0; hh < 4; ++hh) {
      float4 o0, o1;
      o0.x = fmaxf(acc[hh][0] + bv[hh], 0.0f);
      o0.y = fmaxf(acc[hh][1] + bv[hh], 0.0f);
      o0.z = fmaxf(acc[hh][2] + bv[hh], 0.0f);
      o0.w = fmaxf(acc[hh][3] + bv[hh], 0.0f);
      o1.x = fmaxf(acc[hh][4] + bv[hh], 0.0f);
      o1.y = fmaxf(acc[hh][5] + bv[hh], 0.0f);
      o1.z = fmaxf(acc[hh][6] + bv[hh], 0.0f);
      o1.w = fmaxf(acc[hh][7] + bv[hh], 0.0f);
      *(float4*)&bufA[(h0+hh)*68 + j0] = o0;
      *(float4*)&bufA[(h0+hh)*68 + j0 + 4] = o1;
    }
  }
  const int c0 = hg << 3;             // stage C: 8j x 8c
  float acc2[8][8];                   // [c][j]
#pragma unroll
  for (int c = 0; c < 8; ++c)
#pragma unroll
    for (int j = 0; j < 8; ++j) acc2[c][j] = 0.0f;
  for (int hc = 0; hc < 64; hc += 16) {
    __syncthreads();                  // h1T ready / prior chunk consumed
    for (int e = t; e < 16*128; e += 128) {
      int hh = e >> 7, c = e & 127;
      bufB[hh*136 + c] = W2[(size_t)(hc+hh)*128 + c];
    }
    __syncthreads();
#pragma unroll
    for (int h = 0; h < 16; ++h) {
      const float4 ja = *(const float4*)&bufA[(hc+h)*68 + j0];
      const float4 jb = *(const float4*)&bufA[(hc+h)*68 + j0 + 4];
      const float4 wa = *(const float4*)&bufB[h*136 + c0];
      const float4 wb = *(const float4*)&bufB[h*136 + c0 + 4];
      const float hv[8] = {ja.x, ja.y, ja.z, ja.w, jb.x, jb.y, jb.z, jb.w};
      const float wv[8] = {wa.x, wa.y, wa.z, wa.w, wb.x, wb.y, wb.z, wb.w};
#pragma unroll
      for (int c = 0; c < 8; ++c)
#pragma unroll
        for (int j = 0; j < 8; ++j)
          acc2[c][j] += wv[c] * hv[j];
    }
  }
  const int cntv = cnt_s;
  const float4 b2a = *(const float4*)&b2[c0];
  const float4 b2b = *(const float4*)&b2[c0 + 4];
  const float bv2[8] = {b2a.x, b2a.y, b2a.z, b2a.w, b2b.x, b2b.y, b2b.z, b2b.w};
  float best[8];
#pragma unroll
  for (int c = 0; c < 8; ++c) {
    float v = -3.402823466e+38f;
#pragma unroll
    for (int j = 0; j < 8; ++j) {
      float hv = fmaxf(acc2[c][j] + bv2[c], 0.0f);
      v = (j0 + j < cntv) ? fmaxf(v, hv) : v;
    }
    best[c] = v;
  }
#pragma unroll
  for (int off = 1; off < 8; off <<= 1)
#pragma unroll
    for (int c = 0; c < 8; ++c)
      best[c] = fmaxf(best[c], __shfl_xor(best[c], off));
  if (jg == 0) {
    float4 o0 = {best[0], best[1], best[2], best[3]};
    float4 o1 = {best[4], best[5], best[6], best[7]};
    *(float4*)&dout[(size_t)m*128 + c0] = o0;
    *(float4*)&dout[(size_t)m*128 + c0 + 4] = o1;
  }
}

extern "C" void kernel_launch(void* const* d_in, const int* in_sizes, int n_in,
                              void* d_out, int out_size, void* d_ws, size_t ws_size,
                              hipStream_t stream) {
  const float* x   = (const float*)d_in[0];
  const float* pos = (const float*)d_in[1];
  // d_in[2] = batch (layout known statically, unused)
  const float* W1  = (const float*)d_in[3];
  const float* b1  = (const float*)d_in[4];
  const float* W2  = (const float*)d_in[5];
  const float* b2  = (const float*)d_in[6];
  float* dout = (float*)d_out;
  unsigned short* nbr = (unsigned short*)d_ws;
  int* cnt = (int*)((char*)d_ws + (size_t)MTOT*KNB*2);

  hipLaunchKernelGGL(k_fps,    dim3(NB),     dim3(FPS_T), 0, stream, pos, dout);
  hipLaunchKernelGGL(k_radius, dim3(MTOT/4), dim3(256),   0, stream, pos, dout, nbr, cnt);
  hipLaunchKernelGGL(k_conv,   dim3(MTOT),   dim3(128),   0, stream,
                     x, pos, W1, b1, W2, b2, nbr, cnt, dout);
}

// Round 4
// 4494.316 us; speedup vs baseline: 2.2722x; 1.2624x over previous
//
#include <hip/hip_runtime.h>
#include <stdint.h>

#define NPER 8192
#define NB 4
#define MPER 4096
#define MTOT (NB*MPER)      // 16384
#define KNB 64
#define CIN 64
#define R2C 0.04f           // f32-nearest of python 0.2*0.2 (NOT 0.2f*0.2f!)

// d_out (floats): x_out [MTOT*128] | pos_out [MTOT*3] | batch_out [MTOT]
#define POSOUT_OFF (MTOT*128)
#define BATCH_OFF  (MTOT*128 + MTOT*3)

// ws: nbr u16 [MTOT*64] @0 (2MB) | cnt i32 [MTOT] @2MB (64KB)
// fps scratch: first 512 KB of the x_out region of d_out (float4[8192] per
// cloud) -- k_conv overwrites all of x_out afterwards, so this is free.

// ---------------------------------------------------------------- K1: FPS
// Exact lazy FPS. Setup: Morton-cell (8x8x8) counting sort of the cloud into
// global scratch; each thread owns 8 spatially-compact points + register AABB.
// Per iter: conservative bound lb = dist^2(c, AABB); if lb*0.99988 >= max D
// in box, the exact f32 update provably changes nothing (margin >> rounding)
// -> skip, contribute cached key. Keys: (d2bits<<32)|(8191-origidx); u64 max
// == np.argmax first-max semantics. Wave whose lanes all skip reuses cached
// wave max and skips the shfl chain. One barrier/iter, 3-phase winner slot.
// Update arithmetic identical to numpy: ((dx*dx+dy*dy)+dz*dz), rn, no fma.
#define FPS_T 1024
#define PTS 8
#define NCELL 512

__device__ inline unsigned morton3(unsigned ix, unsigned iy, unsigned iz) {
  unsigned m = 0;
#pragma unroll
  for (int b = 0; b < 3; ++b)
    m |= (((ix >> b) & 1u) << (3*b + 2)) | (((iy >> b) & 1u) << (3*b + 1)) |
         (((iz >> b) & 1u) << (3*b));
  return m;
}

__global__ __launch_bounds__(1024, 4) void k_fps(const float* __restrict__ pos,
                                                 float* __restrict__ dout)
{
  const int b = blockIdx.x;
  const int tid = threadIdx.x;
  const float* pb = pos + (size_t)b * NPER * 3;
  float* qo = dout + POSOUT_OFF + (size_t)b * MPER * 3;
  float4* scr = (float4*)(dout + (size_t)b * (NPER * 4));   // 128 KB/cloud

  __shared__ unsigned long long slotU[3];
  __shared__ unsigned hist[NCELL];
  __shared__ unsigned scan[NCELL];
  __shared__ __align__(16) float qbuf[MPER*3];   // 48 KB centroid buffer

  if (tid < NCELL) hist[tid] = 0u;
  if (tid == 0) { slotU[0] = 0ull; slotU[1] = 0ull; slotU[2] = 0ull; }
  __syncthreads();

  // ---- sort pass 1: count ----
  float sx[PTS], sy[PTS], sz[PTS];
  unsigned cellv[PTS];
#pragma unroll
  for (int k = 0; k < PTS; ++k) {
    int i = k * FPS_T + tid;
    sx[k] = pb[i*3+0]; sy[k] = pb[i*3+1]; sz[k] = pb[i*3+2];
    unsigned ix = min(7u, (unsigned)(int)(sx[k] * 8.0f));
    unsigned iy = min(7u, (unsigned)(int)(sy[k] * 8.0f));
    unsigned iz = min(7u, (unsigned)(int)(sz[k] * 8.0f));
    cellv[k] = morton3(ix, iy, iz);
    atomicAdd(&hist[cellv[k]], 1u);
  }
  __syncthreads();
  // ---- inclusive scan of hist -> scan ----
  if (tid < NCELL) scan[tid] = hist[tid];
  __syncthreads();
  for (int s = 1; s < NCELL; s <<= 1) {
    unsigned v = 0u;
    if (tid >= s && tid < NCELL) v = scan[tid - s];
    __syncthreads();
    if (tid < NCELL) scan[tid] += v;
    __syncthreads();
  }
  if (tid < NCELL) hist[tid] = scan[tid] - hist[tid];   // exclusive starts
  __syncthreads();
  // ---- sort pass 2: scatter (x,y,z, 8191-origidx) to scratch ----
#pragma unroll
  for (int k = 0; k < PTS; ++k) {
    unsigned dst = atomicAdd(&hist[cellv[k]], 1u);
    float4 v;
    v.x = sx[k]; v.y = sy[k]; v.z = sz[k];
    v.w = __uint_as_float((unsigned)(NPER - 1 - (k * FPS_T + tid)));
    scr[dst] = v;
  }
  __threadfence();
  __syncthreads();
  // ---- load my 8 contiguous sorted points + AABB ----
  float X[PTS], Y[PTS], Z[PTS], D[PTS];
  unsigned RK[PTS];
  float bxlo = 3.402823466e+38f, bylo = bxlo, bzlo = bxlo;
  float bxhi = -bxlo, byhi = bxhi, bzhi = bxhi;
#pragma unroll
  for (int k = 0; k < PTS; ++k) {
    float4 v = scr[tid * PTS + k];
    X[k] = v.x; Y[k] = v.y; Z[k] = v.z;
    RK[k] = __float_as_uint(v.w);
    D[k] = 3.402823466e+38f;
    bxlo = fminf(bxlo, v.x); bxhi = fmaxf(bxhi, v.x);
    bylo = fminf(bylo, v.y); byhi = fmaxf(byhi, v.y);
    bzlo = fminf(bzlo, v.z); bzhi = fmaxf(bzhi, v.z);
  }

  // ---- main loop ----
  unsigned long long ukey = 0ull, wkey = 0ull;
  float lmax = 3.402823466e+38f;
  int idx_prev = 0;                   // seed selection = point 0
  for (int m = 1; m < MPER; ++m) {
    const float cx = pb[idx_prev*3+0];
    const float cy = pb[idx_prev*3+1];
    const float cz = pb[idx_prev*3+2];
    if (tid == 0) {                   // record row m-1
      qbuf[(m-1)*3+0] = cx; qbuf[(m-1)*3+1] = cy; qbuf[(m-1)*3+2] = cz;
    }
    if (tid == 1) slotU[(m+1) % 3] = 0ull;     // phase-safe future reset
    // conservative bound: dist^2(c, AABB); margin >> rounding error
    float ax = fmaxf(fmaxf(__fsub_rn(bxlo, cx), __fsub_rn(cx, bxhi)), 0.0f);
    float ay = fmaxf(fmaxf(__fsub_rn(bylo, cy), __fsub_rn(cy, byhi)), 0.0f);
    float az = fmaxf(fmaxf(__fsub_rn(bzlo, cz), __fsub_rn(cz, bzhi)), 0.0f);
    float lb = ax*ax + ay*ay + az*az;
    bool upd = (lb * 0.99988f) < lmax;
    if (__ballot(upd) != 0ull) {
      if (upd) {
        unsigned long long bk = 0ull;
#pragma unroll
        for (int k = 0; k < PTS; ++k) {
          float dx = __fsub_rn(X[k], cx);
          float dy = __fsub_rn(Y[k], cy);
          float dz = __fsub_rn(Z[k], cz);
          float s = __fadd_rn(__fadd_rn(__fmul_rn(dx,dx), __fmul_rn(dy,dy)),
                              __fmul_rn(dz,dz));
          float dn = fminf(D[k], s);
          D[k] = dn;
          unsigned long long kk =
            ((unsigned long long)__float_as_uint(dn) << 32) | RK[k];
          bk = (kk > bk) ? kk : bk;
        }
        ukey = bk;
        lmax = __uint_as_float((unsigned)(bk >> 32));
      }
      unsigned long long pkk = ukey;
#pragma unroll
      for (int off = 1; off < 64; off <<= 1) {
        unsigned long long o = __shfl_xor(pkk, off);
        pkk = (o > pkk) ? o : pkk;
      }
      wkey = pkk;
    }
    if ((tid & 63) == 0) atomicMax(&slotU[m % 3], wkey);
    __syncthreads();
    idx_prev = NPER - 1 - (int)(unsigned)(slotU[m % 3] & 0xFFFFFFFFull);
  }
  {                                   // final selection (m = MPER-1)
    const float cx = pb[idx_prev*3+0];
    const float cy = pb[idx_prev*3+1];
    const float cz = pb[idx_prev*3+2];
    if (tid == 0) {
      qbuf[(MPER-1)*3+0] = cx; qbuf[(MPER-1)*3+1] = cy; qbuf[(MPER-1)*3+2] = cz;
    }
  }
  __syncthreads();
  for (int e = tid; e < MPER*3/4; e += FPS_T)
    ((float4*)qo)[e] = ((const float4*)qbuf)[e];
}

// ------------------------------------------------- K2: radius + top-K select
// One wave per centroid. Candidates (d2<=R2) appended via ballot-prefix into
// LDS as u64 key = (d2_bits<<32)|idx (d2>=0 so float bits are order-monotone;
// idx in low bits reproduces top_k's lower-index tie-break). Bitonic sort 512.
#define SCAP 512
__global__ __launch_bounds__(256) void k_radius(const float* __restrict__ pos,
    float* __restrict__ dout, unsigned short* __restrict__ nbr,
    int* __restrict__ cnt)
{
  __shared__ unsigned long long cand[4][SCAP];
  const int wid = threadIdx.x >> 6, lane = threadIdx.x & 63;
  const int m = blockIdx.x * 4 + wid;
  const int b = m >> 12;
  const float* pb = pos + (size_t)b * NPER * 3;
  const float* q = dout + POSOUT_OFF + (size_t)m * 3;
  const float qx = q[0], qy = q[1], qz = q[2];
  unsigned cw = 0;
  for (int it = 0; it < NPER/64; ++it) {
    int i = (it << 6) + lane;
    float dx = __fsub_rn(qx, pb[i*3+0]);
    float dy = __fsub_rn(qy, pb[i*3+1]);
    float dz = __fsub_rn(qz, pb[i*3+2]);
    float d2 = __fadd_rn(__fadd_rn(__fmul_rn(dx,dx), __fmul_rn(dy,dy)),
                         __fmul_rn(dz,dz));
    bool in = (d2 <= R2C);
    unsigned long long mk = __ballot(in);
    unsigned pre = (unsigned)__popcll(mk & ((1ull << lane) - 1ull));
    if (in) {
      unsigned slot = cw + pre;
      if (slot < SCAP)
        cand[wid][slot] =
          (((unsigned long long)__float_as_uint(d2)) << 32) | (unsigned)i;
    }
    cw += (unsigned)__popcll(mk);
  }
  if (cw > SCAP) cw = SCAP;   // statistically unreachable (lambda_max ~274)
  for (int s = (int)cw + lane; s < SCAP; s += 64) cand[wid][s] = ~0ull;
  __syncthreads();
  for (int k = 2; k <= SCAP; k <<= 1) {
    for (int j = k >> 1; j > 0; j >>= 1) {
#pragma unroll
      for (int s = 0; s < SCAP/128; ++s) {
        int t = lane + (s << 6);
        int e = ((t & ~(j-1)) << 1) | (t & (j-1));
        int p = e | j;
        unsigned long long a = cand[wid][e], c = cand[wid][p];
        bool asc = ((e & k) == 0);
        bool sw = asc ? (a > c) : (a < c);
        if (sw) { cand[wid][e] = c; cand[wid][p] = a; }
      }
      __syncthreads();
    }
  }
  int kk = (int)cw; if (kk > KNB) kk = KNB;
  unsigned long long key = cand[wid][lane];
  nbr[(size_t)m*KNB + lane] =
    (lane < kk) ? (unsigned short)(key & 0xFFFFull) : (unsigned short)0;
  if (lane == 0) {
    cnt[m] = kk;
    dout[BATCH_OFF + m] = (float)b;   // batch_out (buffer read as f32)
  }
}

// --------------------------------------------- K3: gather -> MLP -> max (fp32)
// One 128-thr block per centroid. featT[ch][j] (stride 68) + W1 in LDS;
// stage B: 8j x 4h register tile; h1T reuses featT buffer; W2 streamed in
// 16-row chunks through the W1 buffer; stage C: 8j x 8c tile; masked
// shuffle-max over j, write 128 outputs.
__global__ __launch_bounds__(128) void k_conv(
    const float* __restrict__ x, const float* __restrict__ pos,
    const float* __restrict__ W1, const float* __restrict__ b1,
    const float* __restrict__ W2, const float* __restrict__ b2,
    const unsigned short* __restrict__ nbr, const int* __restrict__ cntp,
    float* __restrict__ dout)
{
  __shared__ __align__(16) float bufA[68*68];   // featT then h1T (stride 68)
  __shared__ __align__(16) float bufB[68*68];   // W1 then W2 chunks (str 136)
  __shared__ unsigned short nbr_s[64];
  __shared__ float qv[3];
  __shared__ int cnt_s;
  const int t = threadIdx.x;
  const int m = blockIdx.x;
  const int b = m >> 12;
  if (t < 64) nbr_s[t] = nbr[(size_t)m*KNB + t];
  else if (t == 64) cnt_s = cntp[m];
  else if (t >= 65 && t < 68) qv[t-65] = dout[POSOUT_OFF + (size_t)m*3 + (t-65)];
  for (int e = t; e < 67*64; e += 128) {
    int ch = e >> 6, h = e & 63;
    bufB[ch*68 + h] = W1[e];
  }
  __syncthreads();
  {                                   // gather x rows -> featT rows 0..63
    const int ch = t & 63, jj = t >> 6;
    const size_t xb = (size_t)b * NPER * CIN;
    for (int j0 = 0; j0 < 64; j0 += 2) {
      int j = j0 + jj;
      int r = nbr_s[j];
      bufA[ch*68 + j] = x[xb + (size_t)r*CIN + ch];
    }
  }
  {                                   // rel -> rows 64..66
    const size_t pbb = (size_t)b * NPER * 3;
    for (int e = t; e < 192; e += 128) {
      int j = e & 63, d = e >> 6;
      int r = nbr_s[j];
      bufA[(64+d)*68 + j] = pos[pbb + (size_t)r*3 + d] - qv[d];
    }
  }
  __syncthreads();

  const int jg = t & 7, hg = t >> 3;
  const int j0 = jg << 3;
  const int h0 = hg << 2;
  float acc[4][8];
#pragma unroll
  for (int hh = 0; hh < 4; ++hh)
#pragma unroll
    for (int j = 0; j < 8; ++j) acc[hh][j] = 0.0f;
  for (int ch = 0; ch < 67; ++ch) {
    const float4 fa = *(const float4*)&bufA[ch*68 + j0];
    const float4 fb = *(const float4*)&bufA[ch*68 + j0 + 4];
    const float4 w  = *(const float4*)&bufB[ch*68 + h0];
    const float ws4[4] = {w.x, w.y, w.z, w.w};
    const float fj[8] = {fa.x, fa.y, fa.z, fa.w, fb.x, fb.y, fb.z, fb.w};
#pragma unroll
    for (int hh = 0; hh < 4; ++hh)
#pragma unroll
      for (int j = 0; j < 8; ++j)
        acc[hh][j] += ws4[hh] * fj[j];
  }
  __syncthreads();                    // featT + W1 reads complete
  {                                   // h1T = relu(acc + b1) into bufA
    const float4 bb = *(const float4*)&b1[h0];
    const float bv[4] = {bb.x, bb.y, bb.z, bb.w};
#pragma unroll
    for (int hh = 0; hh < 4; ++hh) {
      float4 o0, o1;
      o0.x = fmaxf(acc[hh][0] + bv[hh], 0.0f);
      o0.y = fmaxf(acc[hh][1] + bv[hh], 0.0f);
      o0.z = fmaxf(acc[hh][2] + bv[hh], 0.0f);
      o0.w = fmaxf(acc[hh][3] + bv[hh], 0.0f);
      o1.x = fmaxf(acc[hh][4] + bv[hh], 0.0f);
      o1.y = fmaxf(acc[hh][5] + bv[hh], 0.0f);
      o1.z = fmaxf(acc[hh][6] + bv[hh], 0.0f);
      o1.w = fmaxf(acc[hh][7] + bv[hh], 0.0f);
      *(float4*)&bufA[(h0+hh)*68 + j0] = o0;
      *(float4*)&bufA[(h0+hh)*68 + j0 + 4] = o1;
    }
  }
  const int c0 = hg << 3;             // stage C: 8j x 8c
  float acc2[8][8];                   // [c][j]
#pragma unroll
  for (int c = 0; c < 8; ++c)
#pragma unroll
    for (int j = 0; j < 8; ++j) acc2[c][j] = 0.0f;
  for (int hc = 0; hc < 64; hc += 16) {
    __syncthreads();                  // h1T ready / prior chunk consumed
    for (int e = t; e < 16*128; e += 128) {
      int hh = e >> 7, c = e & 127;
      bufB[hh*136 + c] = W2[(size_t)(hc+hh)*128 + c];
    }
    __syncthreads();
#pragma unroll
    for (int h = 0; h < 16; ++h) {
      const float4 ja = *(const float4*)&bufA[(hc+h)*68 + j0];
      const float4 jb = *(const float4*)&bufA[(hc+h)*68 + j0 + 4];
      const float4 wa = *(const float4*)&bufB[h*136 + c0];
      const float4 wb = *(const float4*)&bufB[h*136 + c0 + 4];
      const float hv[8] = {ja.x, ja.y, ja.z, ja.w, jb.x, jb.y, jb.z, jb.w};
      const float wv[8] = {wa.x, wa.y, wa.z, wa.w, wb.x, wb.y, wb.z, wb.w};
#pragma unroll
      for (int c = 0; c < 8; ++c)
#pragma unroll
        for (int j = 0; j < 8; ++j)
          acc2[c][j] += wv[c] * hv[j];
    }
  }
  const int cntv = cnt_s;
  const float4 b2a = *(const float4*)&b2[c0];
  const float4 b2b = *(const float4*)&b2[c0 + 4];
  const float bv2[8] = {b2a.x, b2a.y, b2a.z, b2a.w, b2b.x, b2b.y, b2b.z, b2b.w};
  float best[8];
#pragma unroll
  for (int c = 0; c < 8; ++c) {
    float v = -3.402823466e+38f;
#pragma unroll
    for (int j = 0; j < 8; ++j) {
      float hv = fmaxf(acc2[c][j] + bv2[c], 0.0f);
      v = (j0 + j < cntv) ? fmaxf(v, hv) : v;
    }
    best[c] = v;
  }
#pragma unroll
  for (int off = 1; off < 8; off <<= 1)
#pragma unroll
    for (int c = 0; c < 8; ++c)
      best[c] = fmaxf(best[c], __shfl_xor(best[c], off));
  if (jg == 0) {
    float4 o0 = {best[0], best[1], best[2], best[3]};
    float4 o1 = {best[4], best[5], best[6], best[7]};
    *(float4*)&dout[(size_t)m*128 + c0] = o0;
    *(float4*)&dout[(size_t)m*128 + c0 + 4] = o1;
  }
}

extern "C" void kernel_launch(void* const* d_in, const int* in_sizes, int n_in,
                              void* d_out, int out_size, void* d_ws, size_t ws_size,
                              hipStream_t stream) {
  const float* x   = (const float*)d_in[0];
  const float* pos = (const float*)d_in[1];
  // d_in[2] = batch (layout known statically, unused)
  const float* W1  = (const float*)d_in[3];
  const float* b1  = (const float*)d_in[4];
  const float* W2  = (const float*)d_in[5];
  const float* b2  = (const float*)d_in[6];
  float* dout = (float*)d_out;
  unsigned short* nbr = (unsigned short*)d_ws;
  int* cnt = (int*)((char*)d_ws + (size_t)MTOT*KNB*2);

  hipLaunchKernelGGL(k_fps,    dim3(NB),     dim3(FPS_T), 0, stream, pos, dout);
  hipLaunchKernelGGL(k_radius, dim3(MTOT/4), dim3(256),   0, stream, pos, dout, nbr, cnt);
  hipLaunchKernelGGL(k_conv,   dim3(MTOT),   dim3(128),   0, stream,
                     x, pos, W1, b1, W2, b2, nbr, cnt, dout);
}